// Round 10
// baseline (380.040 us; speedup 1.0000x reference)
//
#include <hip/hip_runtime.h>
#include <hip/hip_bf16.h>
#include <math.h>

#define NP 4096     // GRID*GRID
#define NA 256      // stim channels

typedef unsigned short ushort_t;
typedef __attribute__((ext_vector_type(8))) short short8;
typedef __attribute__((ext_vector_type(4))) float f32x4;
typedef __attribute__((ext_vector_type(8))) unsigned short ushort8v;

__device__ __forceinline__ ushort_t f2bf(float x) {
    __hip_bfloat16 h = __float2bfloat16(x);
    return *reinterpret_cast<ushort_t*>(&h);
}
__device__ __forceinline__ float bf2f(ushort_t u) {
    unsigned x = ((unsigned)u) << 16;
    return __builtin_bit_cast(float, x);
}

// ---------------------------------------------------------------------------
// stim [4096 g][256 a] f32 -> stimT [256 a][4096 g] bf16.
// Grid 512 x 256 thr, SAME lid map as field_gemm so each stimT a-panel is
// written entirely by the XCD that will consume it in GEMM0.
// ---------------------------------------------------------------------------
__global__ __launch_bounds__(256)
void transpose_stim(const float* __restrict__ stim, ushort_t* __restrict__ stimT)
{
    __shared__ float lt[64 * 36];
    const int t = threadIdx.x;
    const int v = blockIdx.x;
    const int lid = (v & 7) * 64 + (v >> 3);
    const int g0 = (lid & 63) * 64;
    const int a0 = (lid >> 6) * 32;

    const int gr = t >> 2, ar = (t & 3) * 8;
    *(f32x4*)&lt[gr * 36 + ar]     = *(const f32x4*)&stim[(size_t)(g0 + gr) * NA + a0 + ar];
    *(f32x4*)&lt[gr * 36 + ar + 4] = *(const f32x4*)&stim[(size_t)(g0 + gr) * NA + a0 + ar + 4];
    __syncthreads();
    const int aL = t >> 3, g8 = (t & 7) * 8;
    ushort8v u;
    #pragma unroll
    for (int i = 0; i < 8; ++i) u[i] = f2bf(lt[(g8 + i) * 36 + aL]);
    *(ushort8v*)&stimT[(size_t)(a0 + aL) * NP + g0 + g8] = u;
}

// ---------------------------------------------------------------------------
// Transposed-output separable-field GEMM, 2-blocks/CU variant.
// C^T[a,p] = sum_g B[g,a] * gy[p][gi] * gx[p][gj]
// Tile 64p x 32a; 256 thr = 4 waves = 2 asub x 2 kh; grid 512 (2 blocks/CU).
// lid=(v&7)*64+(v>>3): p0=(lid&63)*64, a0=(lid>>6)*32 -> one a-panel per XCD.
// LDS (73984 B): lB 6 bufs x [2 kh][32 a][64 g] bf16 = 48 KB @0
//                lgxb bf16 [64 p][64 j] swizzled = 8 KB @49152
//                lgy2 f32 [64 gi][64] swizzled = 16 KB @57344
//                latt f32 [64] @73728
// Schedule/phase (16 phases, 2 tt each): vmcnt(4) -> barrier -> STAGE 2 tiles
// (2ph+4,5; NBUF=6 reuse-distance safe because stage is post-barrier) ->
// ds_read A0/A1/s4 -> 16 MFMA.  vmcnt(0) at ph=15.
// acc[pt][r]:  p = p0 + pt*16 + r16 (MFMA col),  a = a0 + asub*16 + q*4 + r.
// MODE 0: C=num=dot*att[p], CT=bf16(num)^T
// MODE 1: C=surr=dot; C2=pn=num/(surr+.5); CT=bf16(pn)^T
// MODE 2: C=pv=dot
// ---------------------------------------------------------------------------
template <int MODE>
__global__ __launch_bounds__(256, 2)
void field_gemm(const ushort_t* __restrict__ bT,
                const float* __restrict__ pscale,
                const float* __restrict__ pasig,
                const float* __restrict__ pagain,
                const float* __restrict__ pssf,
                const float* __restrict__ psff,
                const float* __restrict__ num,      // MODE 1 input
                float* __restrict__ C,
                float* __restrict__ C2,
                ushort_t* __restrict__ CT,
                const ushort_t* __restrict__ numTsrc)
{
    __shared__ __align__(16) unsigned char smem[73984];
    ushort_t* lB   = (ushort_t*)smem;             // [6][2][32][64] bf16
    ushort_t* lgxb = (ushort_t*)(smem + 49152);   // [64 p][64 j] bf16 swizzled
    float*    lgy2 = (float*)(smem + 57344);      // [64 gi][64] f32 swizzled
    float*    latt = (float*)(smem + 73728);

    const int t    = threadIdx.x;
    const int w    = t >> 6;          // wave 0..3
    const int l    = t & 63;
    const int asub = w >> 1;          // 0..1
    const int kh   = w & 1;           // K-half (gi parity)
    const int r16  = l & 15;
    const int q    = l >> 4;          // 0..3
    const int srow  = l >> 3;         // 0..7
    const int sslot = (l & 7) ^ (srow & 7);

    const int v   = blockIdx.x;
    const int lid = (v & 7) * 64 + (v >> 3);
    const int p0  = (lid & 63) * 64;
    const int a0  = (lid >> 6) * 32;

    const float sc_scale = pscale[0];
    const float fac = (MODE == 0) ? 1.0f : (MODE == 1 ? pssf[0] : psff[0]);

#define STAGE(buf, tt)                                                         \
    _Pragma("unroll")                                                          \
    for (int h = 0; h < 2; ++h) {                                              \
        const ushort_t* src = bT + (size_t)(a0 + w * 8 + srow) * NP            \
                              + (2 * (tt) + h) * 64 + sslot * 8;               \
        ushort_t* dst = lB + (buf) * 4096 + h * 2048 + w * 512;                \
        __builtin_amdgcn_global_load_lds(                                      \
            (const __attribute__((address_space(1))) unsigned int*)src,        \
            (__attribute__((address_space(3))) unsigned int*)dst, 16, 0, 0);   \
    }

    // prologue: 4 tiles in flight while tables are computed
    STAGE(0, 0); STAGE(1, 1); STAGE(2, 2); STAGE(3, 3);

    // ---- in-block table generation (closed form) ----
    const float step = 20.0f / 63.0f;
    const float coord = -10.0f + step * (float)l;
    #pragma unroll
    for (int i = 0; i < 16; ++i) {
        const int pl = w * 16 + i, p = p0 + pl;
        float cx = -10.0f + step * (float)(p & 63);
        float cy = -10.0f + step * (float)(p >> 6);
        float sg = (0.07f + sc_scale * sqrtf(cx * cx + cy * cy)) * fac;
        float inv = 1.0f / (2.0f * sg * sg);
        float dx = coord - cx, dy = coord - cy;
        float ex = expf(-dx * dx * inv);
        float ey = expf(-dy * dy * inv);
        float sx = ex, sy = ey;
        #pragma unroll
        for (int o = 32; o > 0; o >>= 1) {
            sx += __shfl_xor(sx, o);
            sy += __shfl_xor(sy, o);
        }
        // lgxb bf16, XOR-swizzled (ushort idx): pl*64 + (j ^ ((pl&7)<<3))
        lgxb[pl * 64 + (l ^ ((pl & 7) << 3))] = f2bf(ex / sx);
        // lgy2 swizzled: consumed as f32x4 at gi*64 + ((r16*4)^((gi&7)<<3)) + pt
        lgy2[l * 64 + (((pl & 15) * 4) ^ ((l & 7) << 3)) + (pl >> 4)] = ey / sy;
        if (MODE == 0 && l == 0) {
            float asig = pasig[0];
            float d2 = (cx - 3.0f) * (cx - 3.0f) + cy * cy;
            latt[pl] = pagain[0] * expf(-d2 / (2.0f * asig * asig)) + 1.0f;
        }
    }
    __syncthreads();   // tables visible; drains prologue DMA (vmcnt->0)

    // B-operand fragments (gx), K-invariant: direct bf16 b128 reads
    short8 gxf[4][2];
    #pragma unroll
    for (int pt = 0; pt < 4; ++pt) {
        const int row = pt * 16 + r16;
        #pragma unroll
        for (int c = 0; c < 2; ++c)
            gxf[pt][c] = *(const short8*)&lgxb[row * 64 +
                            ((c * 32 + q * 8) ^ ((row & 7) << 3))];
    }

    const int n   = asub * 16 + r16;                     // A-row (a_local)
    const int bo0 = n * 64 + ((q ^ (n & 7)) * 8);        // k 0..31 (swizzled)
    const int bo1 = n * 64 + (((4 + q) ^ (n & 7)) * 8);  // k 32..63

    f32x4 acc[4];
    #pragma unroll
    for (int pt = 0; pt < 4; ++pt) acc[pt] = (f32x4){0.f, 0.f, 0.f, 0.f};

    int bufr = 0;   // buf of tile 2ph (mod 6)
    for (int ph = 0; ph < 16; ++ph) {
        if (ph < 15) {
            asm volatile("s_waitcnt vmcnt(4)" ::: "memory");
        } else {
            asm volatile("s_waitcnt vmcnt(0)" ::: "memory");
        }
        __builtin_amdgcn_s_barrier();

        if (ph <= 13) {            // stage tiles 2ph+4, 2ph+5 (post-barrier:
            int bs0 = bufr + 4;    //  their bufs were last read at ph-1)
            if (bs0 >= 6) bs0 -= 6;
            int bs1 = bs0 + 1;
            if (bs1 >= 6) bs1 -= 6;
            STAGE(bs0, 2 * ph + 4);
            STAGE(bs1, 2 * ph + 5);
        }

        #pragma unroll
        for (int u = 0; u < 2; ++u) {
            int buf = bufr + u;
            if (buf >= 6) buf -= 6;
            const int tt = 2 * ph + u;
            const ushort_t* bb = lB + buf * 4096 + kh * 2048;
            short8 A0 = *(const short8*)(bb + bo0);
            short8 A1 = *(const short8*)(bb + bo1);
            const int gi = 2 * tt + kh;
            f32x4 s4 = *(const f32x4*)(lgy2 + gi * 64 +
                                       ((r16 * 4) ^ ((gi & 7) << 3)));
            __builtin_amdgcn_s_setprio(1);
            #pragma unroll
            for (int pt = 0; pt < 4; ++pt) {
                f32x4 tmp = (f32x4){0.f, 0.f, 0.f, 0.f};
                tmp = __builtin_amdgcn_mfma_f32_16x16x32_bf16(A0, gxf[pt][0], tmp, 0, 0, 0);
                tmp = __builtin_amdgcn_mfma_f32_16x16x32_bf16(A1, gxf[pt][1], tmp, 0, 0, 0);
                float sc = s4[pt];
                acc[pt] += tmp * sc;
            }
            __builtin_amdgcn_s_setprio(0);
        }
        bufr += 2;
        if (bufr >= 6) bufr -= 6;
    }
#undef STAGE

    // ---- epilogue: dual-layout LDS reduce (aliases dead lB) ----
    __syncthreads();
    float* lred_ap = (float*)smem;              // [2 kh][32 a][68 p]
    float* lred_pa = (float*)(smem + 17408);    // [2 kh][64 p][36 a]

    const int a_base = asub * 16 + q * 4;       // acc[pt][r] -> a = a_base + r
    #pragma unroll
    for (int pt = 0; pt < 4; ++pt) {
        const int p_idx = pt * 16 + r16;        // acc[pt][*] -> p = p_idx
        *(f32x4*)&lred_pa[(kh * 64 + p_idx) * 36 + a_base] = acc[pt];
        #pragma unroll
        for (int r = 0; r < 4; ++r)
            lred_ap[(kh * 32 + a_base + r) * 68 + p_idx] = acc[pt][r];
    }
    __syncthreads();

    // pass A: a-major -> CT (bf16 transposed), 16B coalesced
    if (MODE != 2) {
        const int aL = t >> 3, p8 = (t & 7) * 8;
        f32x4 s0 = *(f32x4*)&lred_ap[aL * 68 + p8] +
                   *(f32x4*)&lred_ap[(32 + aL) * 68 + p8];
        f32x4 s1 = *(f32x4*)&lred_ap[aL * 68 + p8 + 4] +
                   *(f32x4*)&lred_ap[(32 + aL) * 68 + p8 + 4];
        ushort8v cv;
        if (MODE == 0) {
            f32x4 t0 = *(f32x4*)&latt[p8];
            f32x4 t1 = *(f32x4*)&latt[p8 + 4];
            s0 *= t0; s1 *= t1;
            #pragma unroll
            for (int r = 0; r < 4; ++r) {
                cv[r] = f2bf(s0[r]);
                cv[4 + r] = f2bf(s1[r]);
            }
        } else {
            ushort8v nt = *(const ushort8v*)&numTsrc[(size_t)(a0 + aL) * NP + p0 + p8];
            #pragma unroll
            for (int r = 0; r < 4; ++r) {
                cv[r] = f2bf(bf2f(nt[r]) / (s0[r] + 0.5f));
                cv[4 + r] = f2bf(bf2f(nt[4 + r]) / (s1[r] + 0.5f));
            }
        }
        *(ushort8v*)&CT[(size_t)(a0 + aL) * NP + p0 + p8] = cv;
    }

    // pass B: p-major -> C (f32), coalesced f32x4 rows
    {
        const int pL = t >> 2, a8 = (t & 3) * 8;
        f32x4 s0 = *(f32x4*)&lred_pa[pL * 36 + a8] +
                   *(f32x4*)&lred_pa[(64 + pL) * 36 + a8];
        f32x4 s1 = *(f32x4*)&lred_pa[pL * 36 + a8 + 4] +
                   *(f32x4*)&lred_pa[(64 + pL) * 36 + a8 + 4];
        float* cbase = C + (size_t)(p0 + pL) * NA + a0 + a8;
        if (MODE == 0) {
            float att = latt[pL];
            s0 *= att; s1 *= att;
            *(f32x4*)cbase = s0;
            *(f32x4*)(cbase + 4) = s1;
        } else if (MODE == 1) {
            *(f32x4*)cbase = s0;                      // surround
            *(f32x4*)(cbase + 4) = s1;
            const float* nb = num + (size_t)(p0 + pL) * NA + a0 + a8;
            f32x4 n0 = *(const f32x4*)nb;
            f32x4 n1 = *(const f32x4*)(nb + 4);
            f32x4 o0 = n0 / (s0 + 0.5f);
            f32x4 o1 = n1 / (s1 + 0.5f);
            float* c2 = C2 + (size_t)(p0 + pL) * NA + a0 + a8;
            *(f32x4*)c2 = o0;                         // predicted_neural
            *(f32x4*)(c2 + 4) = o1;
        } else {
            *(f32x4*)cbase = s0;                      // predicted_voxel
            *(f32x4*)(cbase + 4) = s1;
        }
    }
}

extern "C" void kernel_launch(void* const* d_in, const int* in_sizes, int n_in,
                              void* d_out, int out_size, void* d_ws, size_t ws_size,
                              hipStream_t stream)
{
    const float* stim   = (const float*)d_in[0];
    const float* pscale = (const float*)d_in[1];
    const float* pasig  = (const float*)d_in[2];
    const float* pagain = (const float*)d_in[3];
    const float* pssf   = (const float*)d_in[4];
    const float* psff   = (const float*)d_in[5];

    float* out  = (float*)d_out;
    float* num  = out;
    float* surr = out + (size_t)NP * NA;
    float* pn   = out + 2 * (size_t)NP * NA;
    float* pv   = out + 3 * (size_t)NP * NA;

    ushort_t* stimT = (ushort_t*)d_ws;                    // NA*NP bf16 (2MB)
    ushort_t* numT  = stimT + (size_t)NA * NP;            // 2MB
    ushort_t* pnT   = numT + (size_t)NA * NP;             // 2MB

    transpose_stim<<<512, 256, 0, stream>>>(stim, stimT);

    field_gemm<0><<<512, 256, 0, stream>>>(stimT, pscale, pasig, pagain, pssf,
                                           psff, nullptr, num, nullptr, numT,
                                           nullptr);
    field_gemm<1><<<512, 256, 0, stream>>>(numT, pscale, pasig, pagain, pssf,
                                           psff, num, surr, pn, pnT, numT);
    field_gemm<2><<<512, 256, 0, stream>>>(pnT, pscale, pasig, pagain, pssf,
                                           psff, nullptr, pv, nullptr, nullptr,
                                           nullptr);
}

// Round 11
// 65.517 us; speedup vs baseline: 5.8007x; 5.8007x over previous
//
#include <hip/hip_runtime.h>
#include <hip/hip_bf16.h>
#include <math.h>

#define NP 4096     // GRID*GRID
#define NA 256      // stim channels

typedef unsigned short ushort_t;
typedef __attribute__((ext_vector_type(8))) short short8;
typedef __attribute__((ext_vector_type(4))) float f32x4;
typedef __attribute__((ext_vector_type(8))) unsigned short ushort8v;

__device__ __forceinline__ ushort_t f2bf(float x) {
    __hip_bfloat16 h = __float2bfloat16(x);
    return *reinterpret_cast<ushort_t*>(&h);
}
__device__ __forceinline__ float bf2f(ushort_t u) {
    unsigned x = ((unsigned)u) << 16;
    return __builtin_bit_cast(float, x);
}

// ---------------------------------------------------------------------------
// setup_all, grid 448 x 512 thr:
//  blocks [0,256):   stim [4096 g][256 a] f32 -> stimT [256 a][4096 g] bf16
//  blocks [256,448): table images, one (field f, p-block pblk) per block:
//    gxbI [f][pblk][64 row][64 j]  bf16  — per-lane MFMA B-frag-ready
//    gy2I [f][pblk][4096]          f32   — pre-swizzled lgy2 image
//    attI [4096]                   f32   (f==0 only)
// ---------------------------------------------------------------------------
__global__ __launch_bounds__(512)
void setup_all(const float* __restrict__ stim,
               const float* __restrict__ pscale,
               const float* __restrict__ pasig,
               const float* __restrict__ pagain,
               const float* __restrict__ pssf,
               const float* __restrict__ psff,
               ushort_t* __restrict__ stimT,
               ushort_t* __restrict__ gxbI,
               float* __restrict__ gy2I,
               float* __restrict__ attI)
{
    __shared__ float lt[64 * 68];
    const int t = threadIdx.x;
    const int bx = blockIdx.x;
    const float step = 20.0f / 63.0f;

    if (bx < 256) {
        const int g0 = (bx & 63) * 64, a0 = (bx >> 6) * 64;
        const int gr = t >> 3, ar = (t & 7) * 8;
        *(f32x4*)&lt[gr * 68 + ar]     = *(const f32x4*)&stim[(size_t)(g0 + gr) * NA + a0 + ar];
        *(f32x4*)&lt[gr * 68 + ar + 4] = *(const f32x4*)&stim[(size_t)(g0 + gr) * NA + a0 + ar + 4];
        __syncthreads();
        const int a = t >> 3, c8 = (t & 7) * 8;
        ushort8v u;
        #pragma unroll
        for (int i = 0; i < 8; ++i) u[i] = f2bf(lt[(c8 + i) * 68 + a]);
        *(ushort8v*)&stimT[(size_t)(a0 + a) * NP + g0 + c8] = u;
    } else {
        const int b    = bx - 256;        // 0..191
        const int f    = b >> 6;          // 0..2
        const int pblk = b & 63;
        const int w    = t >> 6;
        const int l    = t & 63;
        const float sc_scale = pscale[0];
        const float fac = (f == 0) ? 1.0f : (f == 1 ? pssf[0] : psff[0]);
        const float coord = -10.0f + step * (float)l;
        ushort_t* gxb = gxbI + ((size_t)f * 64 + pblk) * 4096;
        float*    gy2 = gy2I + ((size_t)f * 64 + pblk) * 4096;

        #pragma unroll
        for (int i = 0; i < 8; ++i) {
            const int pl = w * 8 + i, p = pblk * 64 + pl;
            float cx = -10.0f + step * (float)(p & 63);
            float cy = -10.0f + step * (float)(p >> 6);
            float sg = (0.07f + sc_scale * sqrtf(cx * cx + cy * cy)) * fac;
            float inv = 1.0f / (2.0f * sg * sg);
            float dx = coord - cx, dy = coord - cy;
            float ex = expf(-dx * dx * inv);
            float ey = expf(-dy * dy * inv);
            float sx = ex, sy = ey;
            #pragma unroll
            for (int o = 32; o > 0; o >>= 1) {
                sx += __shfl_xor(sx, o);
                sy += __shfl_xor(sy, o);
            }
            gxb[pl * 64 + l] = f2bf(ex / sx);                       // coalesced
            // pre-swizzled lgy2 image (l = gi):
            gy2[l * 64 + (((pl & 15) * 4) ^ ((l & 7) << 3)) + (pl >> 4)] = ey / sy;
            if (f == 0 && l == 0) {
                float asig = pasig[0];
                float d2 = (cx - 3.0f) * (cx - 3.0f) + cy * cy;
                attI[p] = pagain[0] * expf(-d2 / (2.0f * asig * asig)) + 1.0f;
            }
        }
    }
}

// ---------------------------------------------------------------------------
// Transposed-output separable-field GEMM (r9-verified K-loop, table-free).
// C^T[a,p] = sum_g B[g,a] * gy[p][gi] * gx[p][gj]
// LDS (147712 B): lB 8x16KB bufs [0,131072); lgy2 at +131072 (16KB, copied
// verbatim from the pre-swizzled image via global_load_lds); latt at +147456.
// acc[pt][r]:  p = p0 + pt*16 + r16 (MFMA col),  a = a0 + asub*16 + q*4 + r.
// 8 waves = 4 a-subtiles x 2 K-halves; NBUF=8, 2 tt/phase, counted vmcnt(8).
// MODE 0: C=num=dot*att[p], CT=bf16(num)^T
// MODE 1: C=surr=dot; C2=pn=num/(surr+.5); CT=bf16(pn)^T
// MODE 2: C=pv=dot
// ---------------------------------------------------------------------------
template <int MODE>
__global__ __launch_bounds__(512)
void field_gemm(const ushort_t* __restrict__ bT,
                const ushort_t* __restrict__ gxbF,   // field-offset image
                const float* __restrict__ gy2F,      // field-offset image
                const float* __restrict__ attI,
                const float* __restrict__ num,       // MODE 1 input
                float* __restrict__ C,
                float* __restrict__ C2,
                ushort_t* __restrict__ CT,
                const ushort_t* __restrict__ numTsrc)
{
    __shared__ __align__(16) unsigned char smem[147712];
    ushort_t* lB   = (ushort_t*)smem;
    float*    lgy2 = (float*)(smem + 131072);
    float*    latt = (float*)(smem + 147456);

    const int t    = threadIdx.x;
    const int w    = t >> 6;
    const int l    = t & 63;
    const int asub = w >> 1;
    const int kh   = w & 1;
    const int r16  = l & 15;
    const int q    = l >> 4;
    const int srow  = l >> 3;
    const int sslot = (l & 7) ^ (srow & 7);

    // XCD-clustered bijective tile swizzle (256 blocks, 8 XCDs)
    const int v    = blockIdx.x;
    const int lid  = (v & 7) * 32 + (v >> 3);
    const int pblk = lid & 63;
    const int p0   = pblk * 64;
    const int a0   = (lid >> 6) * 64;

#define STAGE(buf, tt)                                                         \
    _Pragma("unroll")                                                          \
    for (int h = 0; h < 2; ++h) {                                              \
        const ushort_t* src = bT + (size_t)(a0 + w * 8 + srow) * NP            \
                              + (2 * (tt) + h) * 64 + sslot * 8;               \
        ushort_t* dst = lB + ((buf) * 2 + h) * 4096 + (w * 8) * 64;            \
        __builtin_amdgcn_global_load_lds(                                      \
            (const __attribute__((address_space(1))) unsigned int*)src,        \
            (__attribute__((address_space(3))) unsigned int*)dst, 16, 0, 0);   \
    }

    // 4 tiles in flight
    STAGE(0, 0); STAGE(1, 1); STAGE(2, 2); STAGE(3, 3);

    // lgy2: verbatim DMA copy of the pre-swizzled image (16 KB, zero VALU)
    {
        const float* gsrc = gy2F + (size_t)pblk * 4096;
        #pragma unroll
        for (int r = 0; r < 2; ++r) {
            const float* src = gsrc + (w * 2 + r) * 256 + l * 4;
            float* dst = lgy2 + (w * 2 + r) * 256;
            __builtin_amdgcn_global_load_lds(
                (const __attribute__((address_space(1))) unsigned int*)src,
                (__attribute__((address_space(3))) unsigned int*)dst, 16, 0, 0);
        }
    }
    if (MODE == 0 && w == 0) {
        const float* src = attI + p0 + l;
        __builtin_amdgcn_global_load_lds(
            (const __attribute__((address_space(1))) unsigned int*)src,
            (__attribute__((address_space(3))) unsigned int*)latt, 4, 0, 0);
    }

    // B-operand fragments (gx): straight register loads from the bf16 image
    const ushort_t* gxb = gxbF + (size_t)pblk * 4096;
    short8 gxf[4][2];
    #pragma unroll
    for (int pt = 0; pt < 4; ++pt) {
        const int row = pt * 16 + r16;
        gxf[pt][0] = *(const short8*)&gxb[row * 64 + q * 8];
        gxf[pt][1] = *(const short8*)&gxb[row * 64 + 32 + q * 8];
    }

    __syncthreads();   // drains all prologue DMA (vmcnt->0) + syncs block

    const int n   = asub * 16 + r16;
    const int bo0 = n * 64 + ((q ^ (n & 7)) * 8);
    const int bo1 = n * 64 + (((4 + q) ^ (n & 7)) * 8);

    f32x4 acc[4];
    #pragma unroll
    for (int pt = 0; pt < 4; ++pt) acc[pt] = (f32x4){0.f, 0.f, 0.f, 0.f};

    for (int ph = 0; ph < 16; ++ph) {
        if (ph <= 13) {
            STAGE((2 * ph + 4) & 7, 2 * ph + 4);
            STAGE((2 * ph + 5) & 7, 2 * ph + 5);
            asm volatile("s_waitcnt vmcnt(8)" ::: "memory");
        } else if (ph == 14) {
            asm volatile("s_waitcnt vmcnt(4)" ::: "memory");
        } else {
            asm volatile("s_waitcnt vmcnt(0)" ::: "memory");
        }
        __builtin_amdgcn_s_barrier();

        #pragma unroll
        for (int u = 0; u < 2; ++u) {
            const int tt = 2 * ph + u;
            const ushort_t* bb = lB + ((tt & 7) * 2 + kh) * 4096;
            short8 A0 = *(const short8*)(bb + bo0);
            short8 A1 = *(const short8*)(bb + bo1);
            const int gi = 2 * tt + kh;
            f32x4 s4 = *(const f32x4*)(lgy2 + gi * 64 +
                                       ((r16 * 4) ^ ((gi & 7) << 3)));
            __builtin_amdgcn_s_setprio(1);
            #pragma unroll
            for (int pt = 0; pt < 4; ++pt) {
                f32x4 tmp = (f32x4){0.f, 0.f, 0.f, 0.f};
                tmp = __builtin_amdgcn_mfma_f32_16x16x32_bf16(A0, gxf[pt][0], tmp, 0, 0, 0);
                tmp = __builtin_amdgcn_mfma_f32_16x16x32_bf16(A1, gxf[pt][1], tmp, 0, 0, 0);
                float sc = s4[pt];
                acc[pt] += tmp * sc;
            }
            __builtin_amdgcn_s_setprio(0);
        }
    }
#undef STAGE

    // ---- epilogue (r9-verified): dual-layout LDS reduce ----
    __syncthreads();   // all lB reads done before aliasing
    float* lred_ap = (float*)smem;              // [2][64 a][68 p]
    float* lred_pa = (float*)(smem + 34816);    // [2][64 p][68 a]

    const int a_base = asub * 16 + q * 4;       // acc[pt][r] -> a = a_base + r
    #pragma unroll
    for (int pt = 0; pt < 4; ++pt) {
        const int p_idx = pt * 16 + r16;        // acc[pt][*] -> p = p_idx
        *(f32x4*)&lred_pa[(kh * 64 + p_idx) * 68 + a_base] = acc[pt];
        #pragma unroll
        for (int r = 0; r < 4; ++r)
            lred_ap[(kh * 64 + a_base + r) * 68 + p_idx] = acc[pt][r];
    }
    __syncthreads();

    // pass A: a-major -> CT (bf16 transposed), 16B coalesced
    if (MODE != 2) {
        const int aL = t >> 3, p8 = (t & 7) * 8;
        f32x4 s0 = *(f32x4*)&lred_ap[aL * 68 + p8] +
                   *(f32x4*)&lred_ap[(64 + aL) * 68 + p8];
        f32x4 s1 = *(f32x4*)&lred_ap[aL * 68 + p8 + 4] +
                   *(f32x4*)&lred_ap[(64 + aL) * 68 + p8 + 4];
        ushort8v cv;
        if (MODE == 0) {
            f32x4 t0 = *(f32x4*)&latt[p8];
            f32x4 t1 = *(f32x4*)&latt[p8 + 4];
            s0 *= t0; s1 *= t1;
            #pragma unroll
            for (int r = 0; r < 4; ++r) {
                cv[r] = f2bf(s0[r]);
                cv[4 + r] = f2bf(s1[r]);
            }
        } else {
            ushort8v nt = *(const ushort8v*)&numTsrc[(size_t)(a0 + aL) * NP + p0 + p8];
            #pragma unroll
            for (int r = 0; r < 4; ++r) {
                cv[r] = f2bf(bf2f(nt[r]) / (s0[r] + 0.5f));
                cv[4 + r] = f2bf(bf2f(nt[4 + r]) / (s1[r] + 0.5f));
            }
        }
        *(ushort8v*)&CT[(size_t)(a0 + aL) * NP + p0 + p8] = cv;
    }

    // pass B: p-major -> C (f32), 256B/row coalesced
    {
        const int pL = t >> 3, a8 = (t & 7) * 8;
        f32x4 s0 = *(f32x4*)&lred_pa[pL * 68 + a8] +
                   *(f32x4*)&lred_pa[(64 + pL) * 68 + a8];
        f32x4 s1 = *(f32x4*)&lred_pa[pL * 68 + a8 + 4] +
                   *(f32x4*)&lred_pa[(64 + pL) * 68 + a8 + 4];
        float* cbase = C + (size_t)(p0 + pL) * NA + a0 + a8;
        if (MODE == 0) {
            float att = latt[pL];
            s0 *= att; s1 *= att;
            *(f32x4*)cbase = s0;
            *(f32x4*)(cbase + 4) = s1;
        } else if (MODE == 1) {
            *(f32x4*)cbase = s0;                      // surround
            *(f32x4*)(cbase + 4) = s1;
            const float* nb = num + (size_t)(p0 + pL) * NA + a0 + a8;
            f32x4 n0 = *(const f32x4*)nb;
            f32x4 n1 = *(const f32x4*)(nb + 4);
            f32x4 o0 = n0 / (s0 + 0.5f);
            f32x4 o1 = n1 / (s1 + 0.5f);
            float* c2 = C2 + (size_t)(p0 + pL) * NA + a0 + a8;
            *(f32x4*)c2 = o0;                         // predicted_neural
            *(f32x4*)(c2 + 4) = o1;
        } else {
            *(f32x4*)cbase = s0;                      // predicted_voxel
            *(f32x4*)(cbase + 4) = s1;
        }
    }
}

extern "C" void kernel_launch(void* const* d_in, const int* in_sizes, int n_in,
                              void* d_out, int out_size, void* d_ws, size_t ws_size,
                              hipStream_t stream)
{
    const float* stim   = (const float*)d_in[0];
    const float* pscale = (const float*)d_in[1];
    const float* pasig  = (const float*)d_in[2];
    const float* pagain = (const float*)d_in[3];
    const float* pssf   = (const float*)d_in[4];
    const float* psff   = (const float*)d_in[5];

    float* out  = (float*)d_out;
    float* num  = out;
    float* surr = out + (size_t)NP * NA;
    float* pn   = out + 2 * (size_t)NP * NA;
    float* pv   = out + 3 * (size_t)NP * NA;

    // ws layout
    ushort_t* stimT = (ushort_t*)d_ws;                    // 2 MB
    ushort_t* numT  = stimT + (size_t)NA * NP;            // 2 MB
    ushort_t* pnT   = numT + (size_t)NA * NP;             // 2 MB
    ushort_t* gxbI  = pnT + (size_t)NA * NP;              // 1.5 MB (3*64*4096 bf16)
    float*    gy2I  = (float*)(gxbI + (size_t)3 * 64 * 4096);  // 3 MB
    float*    attI  = gy2I + (size_t)3 * 64 * 4096;       // 16 KB

    setup_all<<<448, 512, 0, stream>>>(stim, pscale, pasig, pagain, pssf, psff,
                                       stimT, gxbI, gy2I, attI);

    const ushort_t* gx0 = gxbI;
    const ushort_t* gx1 = gxbI + (size_t)64 * 4096;
    const ushort_t* gx2 = gxbI + (size_t)128 * 4096;
    const float*    gy0 = gy2I;
    const float*    gy1 = gy2I + (size_t)64 * 4096;
    const float*    gy2 = gy2I + (size_t)128 * 4096;

    field_gemm<0><<<256, 512, 0, stream>>>(stimT, gx0, gy0, attI, nullptr,
                                           num, nullptr, numT, nullptr);
    field_gemm<1><<<256, 512, 0, stream>>>(numT, gx1, gy1, attI, num,
                                           surr, pn, pnT, numT);
    field_gemm<2><<<256, 512, 0, stream>>>(pnT, gx2, gy2, attI, nullptr,
                                           pv, nullptr, nullptr, nullptr);
}

// Round 13
// 58.989 us; speedup vs baseline: 6.4426x; 1.1107x over previous
//
#include <hip/hip_runtime.h>
#include <hip/hip_bf16.h>
#include <math.h>

#define NP 4096     // GRID*GRID
#define NA 256      // stim channels

typedef unsigned short ushort_t;
typedef __attribute__((ext_vector_type(8))) short short8;
typedef __attribute__((ext_vector_type(4))) float f32x4;
typedef __attribute__((ext_vector_type(8))) unsigned short ushort8v;

__device__ __forceinline__ ushort_t f2bf(float x) {
    __hip_bfloat16 h = __float2bfloat16(x);
    return *reinterpret_cast<ushort_t*>(&h);
}
__device__ __forceinline__ float bf2f(ushort_t u) {
    unsigned x = ((unsigned)u) << 16;
    return __builtin_bit_cast(float, x);
}

// ---------------------------------------------------------------------------
// setup_all (r11-verified), grid 448 x 512 thr:
//  blocks [0,256):   stim [4096 g][256 a] f32 -> stimT [256 a][4096 g] bf16
//  blocks [256,448): table images, one (field f, p-block pblk) per block:
//    gxbI [f][pblk][64 row][64 j]  bf16  — per-lane MFMA B-frag-ready
//    gy2I [f][pblk][4096]          f32   — pre-swizzled lgy2 image
//    attI [4096]                   f32   (f==0 only)
// ---------------------------------------------------------------------------
__global__ __launch_bounds__(512)
void setup_all(const float* __restrict__ stim,
               const float* __restrict__ pscale,
               const float* __restrict__ pasig,
               const float* __restrict__ pagain,
               const float* __restrict__ pssf,
               const float* __restrict__ psff,
               ushort_t* __restrict__ stimT,
               ushort_t* __restrict__ gxbI,
               float* __restrict__ gy2I,
               float* __restrict__ attI)
{
    __shared__ float lt[64 * 68];
    const int t = threadIdx.x;
    const int bx = blockIdx.x;
    const float step = 20.0f / 63.0f;

    if (bx < 256) {
        const int g0 = (bx & 63) * 64, a0 = (bx >> 6) * 64;
        const int gr = t >> 3, ar = (t & 7) * 8;
        *(f32x4*)&lt[gr * 68 + ar]     = *(const f32x4*)&stim[(size_t)(g0 + gr) * NA + a0 + ar];
        *(f32x4*)&lt[gr * 68 + ar + 4] = *(const f32x4*)&stim[(size_t)(g0 + gr) * NA + a0 + ar + 4];
        __syncthreads();
        const int a = t >> 3, c8 = (t & 7) * 8;
        ushort8v u;
        #pragma unroll
        for (int i = 0; i < 8; ++i) u[i] = f2bf(lt[(c8 + i) * 68 + a]);
        *(ushort8v*)&stimT[(size_t)(a0 + a) * NP + g0 + c8] = u;
    } else {
        const int b    = bx - 256;        // 0..191
        const int f    = b >> 6;          // 0..2
        const int pblk = b & 63;
        const int w    = t >> 6;
        const int l    = t & 63;
        const float sc_scale = pscale[0];
        const float fac = (f == 0) ? 1.0f : (f == 1 ? pssf[0] : psff[0]);
        const float coord = -10.0f + step * (float)l;
        ushort_t* gxb = gxbI + ((size_t)f * 64 + pblk) * 4096;
        float*    gy2 = gy2I + ((size_t)f * 64 + pblk) * 4096;

        #pragma unroll
        for (int i = 0; i < 8; ++i) {
            const int pl = w * 8 + i, p = pblk * 64 + pl;
            float cx = -10.0f + step * (float)(p & 63);
            float cy = -10.0f + step * (float)(p >> 6);
            float sg = (0.07f + sc_scale * sqrtf(cx * cx + cy * cy)) * fac;
            float inv = 1.0f / (2.0f * sg * sg);
            float dx = coord - cx, dy = coord - cy;
            float ex = expf(-dx * dx * inv);
            float ey = expf(-dy * dy * inv);
            float sx = ex, sy = ey;
            #pragma unroll
            for (int o = 32; o > 0; o >>= 1) {
                sx += __shfl_xor(sx, o);
                sy += __shfl_xor(sy, o);
            }
            gxb[pl * 64 + l] = f2bf(ex / sx);                       // coalesced
            // pre-swizzled lgy2 image (l = gi):
            gy2[l * 64 + (((pl & 15) * 4) ^ ((l & 7) << 3)) + (pl >> 4)] = ey / sy;
            if (f == 0 && l == 0) {
                float asig = pasig[0];
                float d2 = (cx - 3.0f) * (cx - 3.0f) + cy * cy;
                attI[p] = pagain[0] * expf(-d2 / (2.0f * asig * asig)) + 1.0f;
            }
        }
    }
}

// ---------------------------------------------------------------------------
// Barrier-free wave-private GEMM.  C^T[a,p] = sum_g B[g,a]*gy[p][gi]*gx[p][gj]
// Each wave (asub 0..3, kh 0..1) stages ONLY the 16 a-rows x kh-half it reads:
// lB[8 buf][2 kh][4 asub][16 row][64 g] bf16 (128 KB). No __syncthreads in the
// K-loop: per-wave counted vmcnt(10) (ring 8, stage distance 6), literal tail
// 8/6/4/2/0. WAR safe: buffer (tt+6)&7 was read at tt-2 (lgkm retired pre-MFMA).
// lgy2 at +131072 (16KB pre-swizzled image via DMA); latt at +147456.
// acc[pt][r]:  p = p0 + pt*16 + r16 (MFMA col),  a = a0 + asub*16 + q*4 + r.
// MODE 0: C=num=dot*att[p], CT=bf16(num)^T
// MODE 1: C=surr=dot; C2=pn=num/(surr+.5); CT=bf16(pn)^T
// MODE 2: C=pv=dot
// ---------------------------------------------------------------------------
template <int MODE>
__global__ __launch_bounds__(512)
void field_gemm(const ushort_t* __restrict__ bT,
                const ushort_t* __restrict__ gxbF,   // field-offset image
                const float* __restrict__ gy2F,      // field-offset image
                const float* __restrict__ attI,
                const float* __restrict__ num,       // MODE 1 input
                float* __restrict__ C,
                float* __restrict__ C2,
                ushort_t* __restrict__ CT,
                const ushort_t* __restrict__ numTsrc)
{
    __shared__ __align__(16) unsigned char smem[147712];
    ushort_t* lB   = (ushort_t*)smem;             // [8][2][4][16][64] bf16
    float*    lgy2 = (float*)(smem + 131072);
    float*    latt = (float*)(smem + 147456);

    const int t    = threadIdx.x;
    const int w    = t >> 6;
    const int l    = t & 63;
    const int asub = w >> 1;          // 0..3
    const int kh   = w & 1;           // K-half (gi parity)
    const int r16  = l & 15;
    const int q    = l >> 4;
    const int srow  = l >> 3;         // 0..7 (row within 8-row half)
    const int sslot = (l & 7) ^ (srow & 7);
    const int base_w = kh * 4096 + asub * 1024;   // wave's region (ushorts)

    // XCD-clustered bijective tile swizzle (256 blocks, 8 XCDs)
    const int v    = blockIdx.x;
    const int lid  = (v & 7) * 32 + (v >> 3);
    const int pblk = lid & 63;
    const int p0   = pblk * 64;
    const int a0   = (lid >> 6) * 64;

    // wave-private stage of tile tn's (kh, asub) quarter: 2 x 1KB DMA
#define STAGE(buf, tn)                                                         \
    _Pragma("unroll")                                                          \
    for (int h = 0; h < 2; ++h) {                                              \
        const ushort_t* src = bT + (size_t)(a0 + asub * 16 + h * 8 + srow) * NP\
                              + (2 * (tn) + kh) * 64 + sslot * 8;              \
        ushort_t* dst = lB + (buf) * 8192 + base_w + h * 512;                  \
        __builtin_amdgcn_global_load_lds(                                      \
            (const __attribute__((address_space(1))) unsigned int*)src,        \
            (__attribute__((address_space(3))) unsigned int*)dst, 16, 0, 0);   \
    }

    // prologue: 6 tiles in flight + tables (one drain for everything)
    STAGE(0, 0); STAGE(1, 1); STAGE(2, 2);
    STAGE(3, 3); STAGE(4, 4); STAGE(5, 5);

    {   // lgy2: verbatim DMA copy of the pre-swizzled image (16 KB)
        const float* gsrc = gy2F + (size_t)pblk * 4096;
        #pragma unroll
        for (int r = 0; r < 2; ++r) {
            const float* src = gsrc + (w * 2 + r) * 256 + l * 4;
            float* dst = lgy2 + (w * 2 + r) * 256;
            __builtin_amdgcn_global_load_lds(
                (const __attribute__((address_space(1))) unsigned int*)src,
                (__attribute__((address_space(3))) unsigned int*)dst, 16, 0, 0);
        }
    }
    if (MODE == 0 && w == 0) {
        const float* src = attI + p0 + l;
        __builtin_amdgcn_global_load_lds(
            (const __attribute__((address_space(1))) unsigned int*)src,
            (__attribute__((address_space(3))) unsigned int*)latt, 4, 0, 0);
    }

    // B-operand fragments (gx): straight register loads from the bf16 image
    const ushort_t* gxb = gxbF + (size_t)pblk * 4096;
    short8 gxf[4][2];
    #pragma unroll
    for (int pt = 0; pt < 4; ++pt) {
        const int row = pt * 16 + r16;
        gxf[pt][0] = *(const short8*)&gxb[row * 64 + q * 8];
        gxf[pt][1] = *(const short8*)&gxb[row * 64 + 32 + q * 8];
    }

    __syncthreads();   // single rendezvous: drains ALL prologue vmem (vmcnt=0)

    const int bo0 = r16 * 64 + ((q ^ (r16 & 7)) * 8);        // k 0..31
    const int bo1 = r16 * 64 + (((4 + q) ^ (r16 & 7)) * 8);  // k 32..63

    f32x4 acc[4];
    #pragma unroll
    for (int pt = 0; pt < 4; ++pt) acc[pt] = (f32x4){0.f, 0.f, 0.f, 0.f};

#define KSTEP(tt_, VM)                                                         \
    {                                                                          \
        const int tt_k = (tt_);                                                \
        asm volatile("s_waitcnt vmcnt(" #VM ")" ::: "memory");                 \
        const ushort_t* bb = lB + (tt_k & 7) * 8192 + base_w;                  \
        short8 A0 = *(const short8*)(bb + bo0);                                \
        short8 A1 = *(const short8*)(bb + bo1);                                \
        const int gi = 2 * tt_k + kh;                                          \
        f32x4 s4 = *(const f32x4*)(lgy2 + gi * 64 +                            \
                                   ((r16 * 4) ^ ((gi & 7) << 3)));             \
        __builtin_amdgcn_s_setprio(1);                                         \
        _Pragma("unroll")                                                      \
        for (int pt = 0; pt < 4; ++pt) {                                       \
            f32x4 tmp = (f32x4){0.f, 0.f, 0.f, 0.f};                           \
            tmp = __builtin_amdgcn_mfma_f32_16x16x32_bf16(A0, gxf[pt][0], tmp, 0, 0, 0); \
            tmp = __builtin_amdgcn_mfma_f32_16x16x32_bf16(A1, gxf[pt][1], tmp, 0, 0, 0); \
            float sc = s4[pt];                                                 \
            acc[pt] += tmp * sc;                                               \
        }                                                                      \
        __builtin_amdgcn_s_setprio(0);                                         \
        if (tt_k <= 25) { STAGE((tt_k + 6) & 7, tt_k + 6); }                   \
    }

    for (int tt = 0; tt < 27; ++tt) KSTEP(tt, 10);
    KSTEP(27, 8); KSTEP(28, 6); KSTEP(29, 4); KSTEP(30, 2); KSTEP(31, 0);
#undef KSTEP
#undef STAGE

    // ---- epilogue (r11-verified): dual-layout LDS reduce ----
    __syncthreads();   // all waves drained (own vmcnt(0)) + reads done
    float* lred_ap = (float*)smem;              // [2][64 a][68 p]
    float* lred_pa = (float*)(smem + 34816);    // [2][64 p][68 a]

    const int a_base = asub * 16 + q * 4;       // acc[pt][r] -> a = a_base + r
    #pragma unroll
    for (int pt = 0; pt < 4; ++pt) {
        const int p_idx = pt * 16 + r16;        // acc[pt][*] -> p = p_idx
        *(f32x4*)&lred_pa[(kh * 64 + p_idx) * 68 + a_base] = acc[pt];
        #pragma unroll
        for (int r = 0; r < 4; ++r)
            lred_ap[(kh * 64 + a_base + r) * 68 + p_idx] = acc[pt][r];
    }
    __syncthreads();

    // pass A: a-major -> CT (bf16 transposed), 16B coalesced
    if (MODE != 2) {
        const int aL = t >> 3, p8 = (t & 7) * 8;
        f32x4 s0 = *(f32x4*)&lred_ap[aL * 68 + p8] +
                   *(f32x4*)&lred_ap[(64 + aL) * 68 + p8];
        f32x4 s1 = *(f32x4*)&lred_ap[aL * 68 + p8 + 4] +
                   *(f32x4*)&lred_ap[(64 + aL) * 68 + p8 + 4];
        ushort8v cv;
        if (MODE == 0) {
            f32x4 t0 = *(f32x4*)&latt[p8];
            f32x4 t1 = *(f32x4*)&latt[p8 + 4];
            s0 *= t0; s1 *= t1;
            #pragma unroll
            for (int r = 0; r < 4; ++r) {
                cv[r] = f2bf(s0[r]);
                cv[4 + r] = f2bf(s1[r]);
            }
        } else {
            ushort8v nt = *(const ushort8v*)&numTsrc[(size_t)(a0 + aL) * NP + p0 + p8];
            #pragma unroll
            for (int r = 0; r < 4; ++r) {
                cv[r] = f2bf(bf2f(nt[r]) / (s0[r] + 0.5f));
                cv[4 + r] = f2bf(bf2f(nt[4 + r]) / (s1[r] + 0.5f));
            }
        }
        *(ushort8v*)&CT[(size_t)(a0 + aL) * NP + p0 + p8] = cv;
    }

    // pass B: p-major -> C (f32), 256B/row coalesced
    {
        const int pL = t >> 3, a8 = (t & 7) * 8;
        f32x4 s0 = *(f32x4*)&lred_pa[pL * 68 + a8] +
                   *(f32x4*)&lred_pa[(64 + pL) * 68 + a8];
        f32x4 s1 = *(f32x4*)&lred_pa[pL * 68 + a8 + 4] +
                   *(f32x4*)&lred_pa[(64 + pL) * 68 + a8 + 4];
        float* cbase = C + (size_t)(p0 + pL) * NA + a0 + a8;
        if (MODE == 0) {
            float att = latt[pL];
            s0 *= att; s1 *= att;
            *(f32x4*)cbase = s0;
            *(f32x4*)(cbase + 4) = s1;
        } else if (MODE == 1) {
            *(f32x4*)cbase = s0;                      // surround
            *(f32x4*)(cbase + 4) = s1;
            const float* nb = num + (size_t)(p0 + pL) * NA + a0 + a8;
            f32x4 n0 = *(const f32x4*)nb;
            f32x4 n1 = *(const f32x4*)(nb + 4);
            f32x4 o0 = n0 / (s0 + 0.5f);
            f32x4 o1 = n1 / (s1 + 0.5f);
            float* c2 = C2 + (size_t)(p0 + pL) * NA + a0 + a8;
            *(f32x4*)c2 = o0;                         // predicted_neural
            *(f32x4*)(c2 + 4) = o1;
        } else {
            *(f32x4*)cbase = s0;                      // predicted_voxel
            *(f32x4*)(cbase + 4) = s1;
        }
    }
}

extern "C" void kernel_launch(void* const* d_in, const int* in_sizes, int n_in,
                              void* d_out, int out_size, void* d_ws, size_t ws_size,
                              hipStream_t stream)
{
    const float* stim   = (const float*)d_in[0];
    const float* pscale = (const float*)d_in[1];
    const float* pasig  = (const float*)d_in[2];
    const float* pagain = (const float*)d_in[3];
    const float* pssf   = (const float*)d_in[4];
    const float* psff   = (const float*)d_in[5];

    float* out  = (float*)d_out;
    float* num  = out;
    float* surr = out + (size_t)NP * NA;
    float* pn   = out + 2 * (size_t)NP * NA;
    float* pv   = out + 3 * (size_t)NP * NA;

    // ws layout
    ushort_t* stimT = (ushort_t*)d_ws;                    // 2 MB
    ushort_t* numT  = stimT + (size_t)NA * NP;            // 2 MB
    ushort_t* pnT   = numT + (size_t)NA * NP;             // 2 MB
    ushort_t* gxbI  = pnT + (size_t)NA * NP;              // 1.5 MB (3*64*4096 bf16)
    float*    gy2I  = (float*)(gxbI + (size_t)3 * 64 * 4096);  // 3 MB
    float*    attI  = gy2I + (size_t)3 * 64 * 4096;       // 16 KB

    setup_all<<<448, 512, 0, stream>>>(stim, pscale, pasig, pagain, pssf, psff,
                                       stimT, gxbI, gy2I, attI);

    const ushort_t* gx0 = gxbI;
    const ushort_t* gx1 = gxbI + (size_t)64 * 4096;
    const ushort_t* gx2 = gxbI + (size_t)128 * 4096;
    const float*    gy0 = gy2I;
    const float*    gy1 = gy2I + (size_t)64 * 4096;
    const float*    gy2 = gy2I + (size_t)128 * 4096;

    field_gemm<0><<<256, 512, 0, stream>>>(stimT, gx0, gy0, attI, nullptr,
                                           num, nullptr, numT, nullptr);
    field_gemm<1><<<256, 512, 0, stream>>>(numT, gx1, gy1, attI, num,
                                           surr, pn, pnT, numT);
    field_gemm<2><<<256, 512, 0, stream>>>(pnT, gx2, gy2, attI, nullptr,
                                           pv, nullptr, nullptr, nullptr);
}

// Round 14
// 57.301 us; speedup vs baseline: 6.6324x; 1.0295x over previous
//
#include <hip/hip_runtime.h>
#include <hip/hip_bf16.h>
#include <math.h>

#define NP 4096     // GRID*GRID
#define NA 256      // stim channels

typedef unsigned short ushort_t;
typedef __attribute__((ext_vector_type(8))) short short8;
typedef __attribute__((ext_vector_type(4))) float f32x4;
typedef __attribute__((ext_vector_type(8))) unsigned short ushort8v;

__device__ __forceinline__ ushort_t f2bf(float x) {
    __hip_bfloat16 h = __float2bfloat16(x);
    return *reinterpret_cast<ushort_t*>(&h);
}
__device__ __forceinline__ float bf2f(ushort_t u) {
    unsigned x = ((unsigned)u) << 16;
    return __builtin_bit_cast(float, x);
}

// ---------------------------------------------------------------------------
// setup_all (r11-verified), grid 448 x 512 thr:
//  blocks [0,256):   stim [4096 g][256 a] f32 -> stimT [256 a][4096 g] bf16
//  blocks [256,448): table images, one (field f, p-block pblk) per block:
//    gxbI [f][pblk][64 row][64 j]  bf16  — per-lane MFMA B-frag-ready
//    gy2I [f][pblk][4096]          f32   — pre-swizzled lgy2 image
//    attI [4096]                   f32   (f==0 only)
// ---------------------------------------------------------------------------
__global__ __launch_bounds__(512)
void setup_all(const float* __restrict__ stim,
               const float* __restrict__ pscale,
               const float* __restrict__ pasig,
               const float* __restrict__ pagain,
               const float* __restrict__ pssf,
               const float* __restrict__ psff,
               ushort_t* __restrict__ stimT,
               ushort_t* __restrict__ gxbI,
               float* __restrict__ gy2I,
               float* __restrict__ attI)
{
    __shared__ float lt[64 * 68];
    const int t = threadIdx.x;
    const int bx = blockIdx.x;
    const float step = 20.0f / 63.0f;

    if (bx < 256) {
        const int g0 = (bx & 63) * 64, a0 = (bx >> 6) * 64;
        const int gr = t >> 3, ar = (t & 7) * 8;
        *(f32x4*)&lt[gr * 68 + ar]     = *(const f32x4*)&stim[(size_t)(g0 + gr) * NA + a0 + ar];
        *(f32x4*)&lt[gr * 68 + ar + 4] = *(const f32x4*)&stim[(size_t)(g0 + gr) * NA + a0 + ar + 4];
        __syncthreads();
        const int a = t >> 3, c8 = (t & 7) * 8;
        ushort8v u;
        #pragma unroll
        for (int i = 0; i < 8; ++i) u[i] = f2bf(lt[(c8 + i) * 68 + a]);
        *(ushort8v*)&stimT[(size_t)(a0 + a) * NP + g0 + c8] = u;
    } else {
        const int b    = bx - 256;        // 0..191
        const int f    = b >> 6;          // 0..2
        const int pblk = b & 63;
        const int w    = t >> 6;
        const int l    = t & 63;
        const float sc_scale = pscale[0];
        const float fac = (f == 0) ? 1.0f : (f == 1 ? pssf[0] : psff[0]);
        const float coord = -10.0f + step * (float)l;
        ushort_t* gxb = gxbI + ((size_t)f * 64 + pblk) * 4096;
        float*    gy2 = gy2I + ((size_t)f * 64 + pblk) * 4096;

        #pragma unroll
        for (int i = 0; i < 8; ++i) {
            const int pl = w * 8 + i, p = pblk * 64 + pl;
            float cx = -10.0f + step * (float)(p & 63);
            float cy = -10.0f + step * (float)(p >> 6);
            float sg = (0.07f + sc_scale * sqrtf(cx * cx + cy * cy)) * fac;
            float inv = 1.0f / (2.0f * sg * sg);
            float dx = coord - cx, dy = coord - cy;
            float ex = expf(-dx * dx * inv);
            float ey = expf(-dy * dy * inv);
            float sx = ex, sy = ey;
            #pragma unroll
            for (int o = 32; o > 0; o >>= 1) {
                sx += __shfl_xor(sx, o);
                sy += __shfl_xor(sy, o);
            }
            gxb[pl * 64 + l] = f2bf(ex / sx);                       // coalesced
            // pre-swizzled lgy2 image (l = gi):
            gy2[l * 64 + (((pl & 15) * 4) ^ ((l & 7) << 3)) + (pl >> 4)] = ey / sy;
            if (f == 0 && l == 0) {
                float asig = pasig[0];
                float d2 = (cx - 3.0f) * (cx - 3.0f) + cy * cy;
                attI[p] = pagain[0] * expf(-d2 / (2.0f * asig * asig)) + 1.0f;
            }
        }
    }
}

// ---------------------------------------------------------------------------
// Barrier-free wave-private GEMM + register double-buffered LDS operands.
// C^T[a,p] = sum_g B[g,a]*gy[p][gi]*gx[p][gj]
// Each wave (asub 0..3, kh 0..1) stages ONLY its 16 a-rows x kh-half:
// lB[8 buf][2 kh][4 asub][16 row][64 g] bf16 (128 KB). No K-loop barriers.
// Reg ping-pong Aa/Ab + s4a/s4b: at step tt, vmcnt(8) guarantees stage tt+1
// landed (4 younger stages = 8 loads may remain) -> prefetch A(tt+1) into the
// idle set -> STAGE(tt+6) -> MFMA on regs loaded last step (ds latency hidden).
// Tail vmcnt: 8@tt<=26, 6,4,2,0. WAR: read buf (tt+1)&7 vs write (tt+6)&7 ok.
// acc[pt][r]:  p = p0 + pt*16 + r16 (MFMA col),  a = a0 + asub*16 + q*4 + r.
// MODE 0: C=num=dot*att[p], CT=bf16(num)^T
// MODE 1: C=surr=dot; C2=pn=num/(surr+.5); CT=bf16(pn)^T
// MODE 2: C=pv=dot
// ---------------------------------------------------------------------------
template <int MODE>
__global__ __launch_bounds__(512)
void field_gemm(const ushort_t* __restrict__ bT,
                const ushort_t* __restrict__ gxbF,   // field-offset image
                const float* __restrict__ gy2F,      // field-offset image
                const float* __restrict__ attI,
                const float* __restrict__ num,       // MODE 1 input
                float* __restrict__ C,
                float* __restrict__ C2,
                ushort_t* __restrict__ CT,
                const ushort_t* __restrict__ numTsrc)
{
    __shared__ __align__(16) unsigned char smem[147712];
    ushort_t* lB   = (ushort_t*)smem;             // [8][2][4][16][64] bf16
    float*    lgy2 = (float*)(smem + 131072);
    float*    latt = (float*)(smem + 147456);

    const int t    = threadIdx.x;
    const int w    = t >> 6;
    const int l    = t & 63;
    const int asub = w >> 1;          // 0..3
    const int kh   = w & 1;           // K-half (gi parity)
    const int r16  = l & 15;
    const int q    = l >> 4;
    const int srow  = l >> 3;         // 0..7 (row within 8-row half)
    const int sslot = (l & 7) ^ (srow & 7);
    const int base_w = kh * 4096 + asub * 1024;   // wave's region (ushorts)

    // XCD-clustered bijective tile swizzle (256 blocks, 8 XCDs)
    const int v    = blockIdx.x;
    const int lid  = (v & 7) * 32 + (v >> 3);
    const int pblk = lid & 63;
    const int p0   = pblk * 64;
    const int a0   = (lid >> 6) * 64;

    // wave-private stage of tile tn's (kh, asub) quarter: 2 x 1KB DMA
#define STAGE(buf, tn)                                                         \
    _Pragma("unroll")                                                          \
    for (int h = 0; h < 2; ++h) {                                              \
        const ushort_t* src = bT + (size_t)(a0 + asub * 16 + h * 8 + srow) * NP\
                              + (2 * (tn) + kh) * 64 + sslot * 8;              \
        ushort_t* dst = lB + (buf) * 8192 + base_w + h * 512;                  \
        __builtin_amdgcn_global_load_lds(                                      \
            (const __attribute__((address_space(1))) unsigned int*)src,        \
            (__attribute__((address_space(3))) unsigned int*)dst, 16, 0, 0);   \
    }

    // prologue: 6 tiles in flight + tables (one drain for everything)
    STAGE(0, 0); STAGE(1, 1); STAGE(2, 2);
    STAGE(3, 3); STAGE(4, 4); STAGE(5, 5);

    {   // lgy2: verbatim DMA copy of the pre-swizzled image (16 KB)
        const float* gsrc = gy2F + (size_t)pblk * 4096;
        #pragma unroll
        for (int r = 0; r < 2; ++r) {
            const float* src = gsrc + (w * 2 + r) * 256 + l * 4;
            float* dst = lgy2 + (w * 2 + r) * 256;
            __builtin_amdgcn_global_load_lds(
                (const __attribute__((address_space(1))) unsigned int*)src,
                (__attribute__((address_space(3))) unsigned int*)dst, 16, 0, 0);
        }
    }
    if (MODE == 0 && w == 0) {
        const float* src = attI + p0 + l;
        __builtin_amdgcn_global_load_lds(
            (const __attribute__((address_space(1))) unsigned int*)src,
            (__attribute__((address_space(3))) unsigned int*)latt, 4, 0, 0);
    }

    // B-operand fragments (gx): straight register loads from the bf16 image
    const ushort_t* gxb = gxbF + (size_t)pblk * 4096;
    short8 gxf[4][2];
    #pragma unroll
    for (int pt = 0; pt < 4; ++pt) {
        const int row = pt * 16 + r16;
        gxf[pt][0] = *(const short8*)&gxb[row * 64 + q * 8];
        gxf[pt][1] = *(const short8*)&gxb[row * 64 + 32 + q * 8];
    }

    __syncthreads();   // single rendezvous: drains ALL prologue vmem (vmcnt=0)

    const int bo0 = r16 * 64 + ((q ^ (r16 & 7)) * 8);        // k 0..31
    const int bo1 = r16 * 64 + (((4 + q) ^ (r16 & 7)) * 8);  // k 32..63

    f32x4 acc[4];
    #pragma unroll
    for (int pt = 0; pt < 4; ++pt) acc[pt] = (f32x4){0.f, 0.f, 0.f, 0.f};

    // explicit ping-pong register sets (rule #20: no runtime-indexed arrays)
    short8 Aa0, Aa1, Ab0, Ab1;
    f32x4 s4a, s4b;
    {   // load step 0 operands (stages 0..5 are resident post-sync)
        const ushort_t* bb0 = lB + base_w;          // buf 0
        Aa0 = *(const short8*)(bb0 + bo0);
        Aa1 = *(const short8*)(bb0 + bo1);
        const int gi0 = kh;
        s4a = *(const f32x4*)(lgy2 + gi0 * 64 + ((r16 * 4) ^ ((gi0 & 7) << 3)));
    }

    // STEP(tt, vmcnt-lit, cur regs, next regs, do-prefetch, do-stage)
#define STEP(TT, VM, CA0, CA1, CS4, NA0, NA1, NS4, PRE, ST)                    \
    {                                                                          \
        const int tt_k = (TT);                                                 \
        asm volatile("s_waitcnt vmcnt(" #VM ")" ::: "memory");                 \
        if (PRE) {                                                             \
            const ushort_t* bbn = lB + ((tt_k + 1) & 7) * 8192 + base_w;       \
            NA0 = *(const short8*)(bbn + bo0);                                 \
            NA1 = *(const short8*)(bbn + bo1);                                 \
            const int gin = 2 * (tt_k + 1) + kh;                               \
            NS4 = *(const f32x4*)(lgy2 + gin * 64 +                            \
                                  ((r16 * 4) ^ ((gin & 7) << 3)));             \
        }                                                                      \
        if (ST) { STAGE((tt_k + 6) & 7, tt_k + 6); }                           \
        __builtin_amdgcn_s_setprio(1);                                         \
        _Pragma("unroll")                                                      \
        for (int pt = 0; pt < 4; ++pt) {                                       \
            f32x4 tmp = (f32x4){0.f, 0.f, 0.f, 0.f};                           \
            tmp = __builtin_amdgcn_mfma_f32_16x16x32_bf16(CA0, gxf[pt][0], tmp, 0, 0, 0); \
            tmp = __builtin_amdgcn_mfma_f32_16x16x32_bf16(CA1, gxf[pt][1], tmp, 0, 0, 0); \
            float sc = CS4[pt];                                                \
            acc[pt] += tmp * sc;                                               \
        }                                                                      \
        __builtin_amdgcn_s_setprio(0);                                         \
    }

    #pragma unroll
    for (int pi = 0; pi < 13; ++pi) {       // tt = 0..25 (all stage)
        STEP(2 * pi,     8, Aa0, Aa1, s4a, Ab0, Ab1, s4b, 1, 1);
        STEP(2 * pi + 1, 8, Ab0, Ab1, s4b, Aa0, Aa1, s4a, 1, 1);
    }
    STEP(26, 8, Aa0, Aa1, s4a, Ab0, Ab1, s4b, 1, 0);
    STEP(27, 6, Ab0, Ab1, s4b, Aa0, Aa1, s4a, 1, 0);
    STEP(28, 4, Aa0, Aa1, s4a, Ab0, Ab1, s4b, 1, 0);
    STEP(29, 2, Ab0, Ab1, s4b, Aa0, Aa1, s4a, 1, 0);
    STEP(30, 0, Aa0, Aa1, s4a, Ab0, Ab1, s4b, 1, 0);
    STEP(31, 0, Ab0, Ab1, s4b, Aa0, Aa1, s4a, 0, 0);
#undef STEP
#undef STAGE

    // ---- epilogue (r11-verified): dual-layout LDS reduce ----
    __syncthreads();   // all waves drained (own vmcnt(0)) + reads done
    float* lred_ap = (float*)smem;              // [2][64 a][68 p]
    float* lred_pa = (float*)(smem + 34816);    // [2][64 p][68 a]

    const int a_base = asub * 16 + q * 4;       // acc[pt][r] -> a = a_base + r
    #pragma unroll
    for (int pt = 0; pt < 4; ++pt) {
        const int p_idx = pt * 16 + r16;        // acc[pt][*] -> p = p_idx
        *(f32x4*)&lred_pa[(kh * 64 + p_idx) * 68 + a_base] = acc[pt];
        #pragma unroll
        for (int r = 0; r < 4; ++r)
            lred_ap[(kh * 64 + a_base + r) * 68 + p_idx] = acc[pt][r];
    }
    __syncthreads();

    // pass A: a-major -> CT (bf16 transposed), 16B coalesced
    if (MODE != 2) {
        const int aL = t >> 3, p8 = (t & 7) * 8;
        f32x4 s0 = *(f32x4*)&lred_ap[aL * 68 + p8] +
                   *(f32x4*)&lred_ap[(64 + aL) * 68 + p8];
        f32x4 s1 = *(f32x4*)&lred_ap[aL * 68 + p8 + 4] +
                   *(f32x4*)&lred_ap[(64 + aL) * 68 + p8 + 4];
        ushort8v cv;
        if (MODE == 0) {
            f32x4 t0 = *(f32x4*)&latt[p8];
            f32x4 t1 = *(f32x4*)&latt[p8 + 4];
            s0 *= t0; s1 *= t1;
            #pragma unroll
            for (int r = 0; r < 4; ++r) {
                cv[r] = f2bf(s0[r]);
                cv[4 + r] = f2bf(s1[r]);
            }
        } else {
            ushort8v nt = *(const ushort8v*)&numTsrc[(size_t)(a0 + aL) * NP + p0 + p8];
            #pragma unroll
            for (int r = 0; r < 4; ++r) {
                cv[r] = f2bf(bf2f(nt[r]) / (s0[r] + 0.5f));
                cv[4 + r] = f2bf(bf2f(nt[4 + r]) / (s1[r] + 0.5f));
            }
        }
        *(ushort8v*)&CT[(size_t)(a0 + aL) * NP + p0 + p8] = cv;
    }

    // pass B: p-major -> C (f32), 256B/row coalesced
    {
        const int pL = t >> 3, a8 = (t & 7) * 8;
        f32x4 s0 = *(f32x4*)&lred_pa[pL * 68 + a8] +
                   *(f32x4*)&lred_pa[(64 + pL) * 68 + a8];
        f32x4 s1 = *(f32x4*)&lred_pa[pL * 68 + a8 + 4] +
                   *(f32x4*)&lred_pa[(64 + pL) * 68 + a8 + 4];
        float* cbase = C + (size_t)(p0 + pL) * NA + a0 + a8;
        if (MODE == 0) {
            float att = latt[pL];
            s0 *= att; s1 *= att;
            *(f32x4*)cbase = s0;
            *(f32x4*)(cbase + 4) = s1;
        } else if (MODE == 1) {
            *(f32x4*)cbase = s0;                      // surround
            *(f32x4*)(cbase + 4) = s1;
            const float* nb = num + (size_t)(p0 + pL) * NA + a0 + a8;
            f32x4 n0 = *(const f32x4*)nb;
            f32x4 n1 = *(const f32x4*)(nb + 4);
            f32x4 o0 = n0 / (s0 + 0.5f);
            f32x4 o1 = n1 / (s1 + 0.5f);
            float* c2 = C2 + (size_t)(p0 + pL) * NA + a0 + a8;
            *(f32x4*)c2 = o0;                         // predicted_neural
            *(f32x4*)(c2 + 4) = o1;
        } else {
            *(f32x4*)cbase = s0;                      // predicted_voxel
            *(f32x4*)(cbase + 4) = s1;
        }
    }
}

extern "C" void kernel_launch(void* const* d_in, const int* in_sizes, int n_in,
                              void* d_out, int out_size, void* d_ws, size_t ws_size,
                              hipStream_t stream)
{
    const float* stim   = (const float*)d_in[0];
    const float* pscale = (const float*)d_in[1];
    const float* pasig  = (const float*)d_in[2];
    const float* pagain = (const float*)d_in[3];
    const float* pssf   = (const float*)d_in[4];
    const float* psff   = (const float*)d_in[5];

    float* out  = (float*)d_out;
    float* num  = out;
    float* surr = out + (size_t)NP * NA;
    float* pn   = out + 2 * (size_t)NP * NA;
    float* pv   = out + 3 * (size_t)NP * NA;

    // ws layout
    ushort_t* stimT = (ushort_t*)d_ws;                    // 2 MB
    ushort_t* numT  = stimT + (size_t)NA * NP;            // 2 MB
    ushort_t* pnT   = numT + (size_t)NA * NP;             // 2 MB
    ushort_t* gxbI  = pnT + (size_t)NA * NP;              // 1.5 MB (3*64*4096 bf16)
    float*    gy2I  = (float*)(gxbI + (size_t)3 * 64 * 4096);  // 3 MB
    float*    attI  = gy2I + (size_t)3 * 64 * 4096;       // 16 KB

    setup_all<<<448, 512, 0, stream>>>(stim, pscale, pasig, pagain, pssf, psff,
                                       stimT, gxbI, gy2I, attI);

    const ushort_t* gx0 = gxbI;
    const ushort_t* gx1 = gxbI + (size_t)64 * 4096;
    const ushort_t* gx2 = gxbI + (size_t)128 * 4096;
    const float*    gy0 = gy2I;
    const float*    gy1 = gy2I + (size_t)64 * 4096;
    const float*    gy2 = gy2I + (size_t)128 * 4096;

    field_gemm<0><<<256, 512, 0, stream>>>(stimT, gx0, gy0, attI, nullptr,
                                           num, nullptr, numT, nullptr);
    field_gemm<1><<<256, 512, 0, stream>>>(numT, gx1, gy1, attI, num,
                                           surr, pn, pnT, numT);
    field_gemm<2><<<256, 512, 0, stream>>>(pnT, gx2, gy2, attI, nullptr,
                                           pv, nullptr, nullptr, nullptr);
}